// Round 1
// baseline (14075.276 us; speedup 1.0000x reference)
//
#include <hip/hip_runtime.h>
#include <hip/hip_bf16.h>
#include <cstdint>
#include <cstddef>

typedef __bf16 bf16;
typedef __bf16 bf16x8 __attribute__((ext_vector_type(8)));
typedef float f32x4 __attribute__((ext_vector_type(4)));

#define B_ 128
#define S_ 512
#define E_ 256
#define H_ 512

// ---- workspace layout (bytes) ----
#define EMB_OFF   0UL
#define EMB_SZ    (128UL*512*256*2)        // 33,554,432  bf16 (B,S,E)
#define HSF_OFF   (EMB_OFF + EMB_SZ)
#define HS_SZ     (512UL*128*512*2)        // 67,108,864  bf16 (S,B,H)
#define HSB_OFF   (HSF_OFF + HS_SZ)
#define LOG_OFF   (HSB_OFF + HS_SZ)
#define LOG_SZ    (512UL*128*32*4)         // 8,388,608   f32 (S,B,T)
#define HPING_OFF (LOG_OFF + LOG_SZ)
#define HPING_SZ  (16UL*2*16*512*2)        // 524,288     bf16 [group][2][16][512]
#define WLIN_OFF  (HPING_OFF + HPING_SZ)
#define WLIN_SZ   (32UL*1024*2)            // 65,536      bf16
#define BAR_OFF   ((WLIN_OFF + WLIN_SZ + 255UL) & ~255UL)
#define BAR_SZ    (16UL*32*4)              // 16 groups * 128B

__device__ __forceinline__ float fsig(float x)  { return 1.0f / (1.0f + __expf(-x)); }
__device__ __forceinline__ float ftanhf(float x){ return 1.0f - 2.0f / (__expf(2.0f * x) + 1.0f); }

// ---------------- K1: embedding gather fp32 -> bf16 ----------------
__global__ void embed_gather(const int* __restrict__ sents,
                             const float* __restrict__ table,
                             bf16* __restrict__ emb) {
    int t = threadIdx.x;
    int row = blockIdx.x * 8 + (t >> 5);       // flat (b,s), 65536 rows
    int e0 = (t & 31) * 8;
    int idx = sents[row];
    const float4* src = (const float4*)(table + (size_t)idx * 256 + e0);
    float4 f0 = src[0], f1 = src[1];
    bf16x8 v;
    v[0]=(bf16)f0.x; v[1]=(bf16)f0.y; v[2]=(bf16)f0.z; v[3]=(bf16)f0.w;
    v[4]=(bf16)f1.x; v[5]=(bf16)f1.y; v[6]=(bf16)f1.z; v[7]=(bf16)f1.w;
    *(bf16x8*)(emb + (size_t)row * 256 + e0) = v;
}

// ---------------- K1b: lin_w fp32 -> bf16 ----------------
__global__ void conv_linw(const float* __restrict__ w, bf16* __restrict__ o) {
    int i = blockIdx.x * 256 + threadIdx.x;    // 32768
    o[i] = (bf16)w[i];
}

// ---------------- K2: persistent bidirectional LSTM ----------------
// grid 256 x 256. 16 groups = (dir, batch-tile of 16); 16 WGs/group (32 hidden units each).
// Per wave: M=16 (batch), N=32 (2 MFMA n-tiles; cols = gate(i,f | g,o) x 8 units), K=768.
// Weights resident in VGPRs (24x2 bf16x8 frags). A staged in LDS in fragment order.
__global__ __launch_bounds__(256, 1) void lstm_persistent(
    const bf16* __restrict__ emb, bf16* __restrict__ hping,
    bf16* __restrict__ hs_f, bf16* __restrict__ hs_b,
    const float* __restrict__ w_ih_f, const float* __restrict__ w_hh_f,
    const float* __restrict__ b_ih_f, const float* __restrict__ b_hh_f,
    const float* __restrict__ w_ih_b, const float* __restrict__ w_hh_b,
    const float* __restrict__ b_ih_b, const float* __restrict__ b_hh_b,
    const int* __restrict__ lengths, int* __restrict__ bar)
{
    const int tid = threadIdx.x;
    const int l   = tid & 63;
    const int wv  = tid >> 6;
    const int bid = blockIdx.x;
    // XCD-friendly group decode: group members share bid%8 (same XCD heuristically)
    const int slot = bid >> 3;
    const int g  = (bid & 7) + ((slot >> 4) << 3);   // 0..15
    const int k  = slot & 15;                        // hidden group 0..15
    const int d  = g >> 3;                           // 0 fwd, 1 bwd
    const int bg = g & 7;                            // batch tile
    const int U0 = k * 32;

    const float* Wih = d ? w_ih_b : w_ih_f;
    const float* Whh = d ? w_hh_b : w_hh_f;
    const float* Bih = d ? b_ih_b : b_ih_f;
    const float* Bhh = d ? b_hh_b : b_hh_f;

    __shared__ uint4 smemA[1536];          // 24 KB: A fragments (24 K-chunks x 64 slots)
    __shared__ float gatesS[16 * 132];     // raw gate pre-activations
    __shared__ float c_sh[512];
    __shared__ float h_sh[512];
    __shared__ int   sh_tmax;

    // ---- weight fragments into VGPRs (once) ----
    bf16x8 wf[24][2];
    {
        const int lane15 = l & 15, q = l >> 4;
        #pragma unroll
        for (int kk = 0; kk < 24; ++kk) {
            #pragma unroll
            for (int T = 0; T < 2; ++T) {
                int c   = T * 16 + lane15;                       // within-wave col 0..31
                int row = (c >> 3) * 512 + U0 + 8 * wv + (c & 7); // W row (gate*512+unit)
                int k0  = kk * 32 + q * 8;
                const float* src = (k0 < 256) ? (Wih + (size_t)row * 256 + k0)
                                              : (Whh + (size_t)row * 512 + (k0 - 256));
                float4 f0 = *(const float4*)src;
                float4 f1 = *(const float4*)(src + 4);
                bf16x8 v;
                v[0]=(bf16)f0.x; v[1]=(bf16)f0.y; v[2]=(bf16)f0.z; v[3]=(bf16)f0.w;
                v[4]=(bf16)f1.x; v[5]=(bf16)f1.y; v[6]=(bf16)f1.z; v[7]=(bf16)f1.w;
                wf[kk][T] = v;
            }
        }
    }

    // ---- per-thread updater setup ----
    const int uu = tid & 31;        // unit within WG (0..31)
    const int ub = tid >> 5;        // 0..7
    float bI, bF, bG, bO;
    {
        int r0 = U0 + uu;
        bI = Bih[r0]        + Bhh[r0];
        bF = Bih[512 + r0]  + Bhh[512 + r0];
        bG = Bih[1024 + r0] + Bhh[1024 + r0];
        bO = Bih[1536 + r0] + Bhh[1536 + r0];
    }
    int lenU0 = lengths[bg * 16 + ub * 2];
    int lenU1 = lengths[bg * 16 + ub * 2 + 1];

    // ---- staging thread setup ----
    const int sr  = tid & 15;       // batch row 0..15
    const int sc0 = tid >> 4;       // chunk col 0..15
    const int lenR = lengths[bg * 16 + sr];
    const bf16* embB = emb + ((size_t)(bg * 16 + sr)) * 512 * 256;

    // ---- zero state ----
    for (int i = tid; i < 512; i += 256) { c_sh[i] = 0.0f; h_sh[i] = 0.0f; }
    bf16* hp = hping + (size_t)g * (2 * 16 * 512);
    {
        int r = tid >> 4, cc = tid & 15;
        *(unsigned int*)(hp + r * 512 + U0 + cc * 2) = 0u;
    }
    if (tid == 0) {
        int mx = 0;
        for (int b2 = 0; b2 < 16; ++b2) mx = max(mx, lengths[bg * 16 + b2]);
        sh_tmax = mx;
    }
    __syncthreads();
    const int tmax = sh_tmax;

    int* cnt = bar + g * 32;
    // prologue group barrier (h buffer 0 zeroed everywhere)
    if (tid == 0) {
        __threadfence();
        __hip_atomic_fetch_add(cnt, 1, __ATOMIC_RELEASE, __HIP_MEMORY_SCOPE_AGENT);
        while (__hip_atomic_load(cnt, __ATOMIC_ACQUIRE, __HIP_MEMORY_SCOPE_AGENT) < 16)
            __builtin_amdgcn_s_sleep(2);
    }
    __syncthreads();
    __threadfence();

    const int sig = 4 * (l & 15) + (l >> 4);

    for (int t = 0; t < tmax; ++t) {
        bf16* hcur = hp + (t & 1) * (16 * 512);
        bf16* hnxt = hp + ((t + 1) & 1) * (16 * 512);

        // ---- stage A (16 x 768 bf16) into fragment-ordered LDS ----
        int pos = (d == 0) ? t : ((t < lenR) ? (lenR - 1 - t) : t);
        const bf16* xsrc = embB + (size_t)pos * 256;
        #pragma unroll
        for (int i = 0; i < 6; ++i) {
            int c = sc0 + 16 * i;                                 // 8-elem chunk id, 0..95
            const bf16* src = (i < 2) ? (xsrc + c * 8)
                                      : (hcur + sr * 512 + (c - 32) * 8);
            uint4 v = *(const uint4*)src;
            smemA[((c >> 2) << 6) + 4 * sr + (c & 3)] = v;
        }
        __syncthreads();

        // ---- MFMA: gates += A * W^T ----
        f32x4 acc0 = {0.f, 0.f, 0.f, 0.f}, acc1 = {0.f, 0.f, 0.f, 0.f};
        #pragma unroll
        for (int kk = 0; kk < 24; ++kk) {
            bf16x8 a = *(const bf16x8*)&smemA[(kk << 6) + sig];
            acc0 = __builtin_amdgcn_mfma_f32_16x16x32_bf16(a, wf[kk][0], acc0, 0, 0, 0);
            acc1 = __builtin_amdgcn_mfma_f32_16x16x32_bf16(a, wf[kk][1], acc1, 0, 0, 0);
        }
        // ---- write gates to LDS, permuted so (i,f,g,o) of a unit are contiguous ----
        {
            int c0l = l & 15;
            int colA = (wv << 5) + ((c0l & 7) << 2) + (c0l >> 3);       // gates 0/1
            int colB = colA + 2;                                        // gates 2/3
            int rbase = (l >> 4) * 4;
            #pragma unroll
            for (int reg = 0; reg < 4; ++reg) {
                gatesS[(rbase + reg) * 132 + colA] = acc0[reg];
                gatesS[(rbase + reg) * 132 + colB] = acc1[reg];
            }
        }
        __syncthreads();

        // ---- cell update (2 (b,u) pairs per thread) ----
        #pragma unroll
        for (int bi = 0; bi < 2; ++bi) {
            int b   = ub * 2 + bi;
            int len = bi ? lenU1 : lenU0;
            float4 gv = *(const float4*)&gatesS[b * 132 + ((uu >> 3) << 5) + ((uu & 7) << 2)];
            float iv = fsig(gv.x + bI);
            float fv = fsig(gv.y + bF);
            float gg = ftanhf(gv.z + bG);
            float ov = fsig(gv.w + bO);
            int si = b * 32 + uu;
            float co = c_sh[si], ho = h_sh[si];
            float cn = fv * co + iv * gg;
            float hn = ov * ftanhf(cn);
            bool m = (t < len);
            float cw = m ? cn : co;
            float hw = m ? hn : ho;
            c_sh[si] = cw; h_sh[si] = hw;
            bf16 hb = (bf16)hw;
            hnxt[b * 512 + U0 + uu] = hb;
            if (d == 0) {
                hs_f[((size_t)t * 128 + bg * 16 + b) * 512 + U0 + uu] = hb;
            } else if (m) {
                hs_b[((size_t)(len - 1 - t) * 128 + bg * 16 + b) * 512 + U0 + uu] = hb;
            }
        }

        // ---- group barrier (release h[t+1]) ----
        __syncthreads();
        if (tid == 0) {
            __threadfence();
            __hip_atomic_fetch_add(cnt, 1, __ATOMIC_RELEASE, __HIP_MEMORY_SCOPE_AGENT);
            int tgt = 16 * (t + 2);
            while (__hip_atomic_load(cnt, __ATOMIC_ACQUIRE, __HIP_MEMORY_SCOPE_AGENT) < tgt)
                __builtin_amdgcn_s_sleep(2);
        }
        __syncthreads();
        __threadfence();
    }
}

// ---------------- K3: logits = [hs_f|hs_b] @ lin_w^T + lin_b ----------------
__global__ __launch_bounds__(256) void logits_kernel(
    const bf16* __restrict__ hs_f, const bf16* __restrict__ hs_b,
    const bf16* __restrict__ wlin, const float* __restrict__ lin_b,
    float* __restrict__ logits)
{
    const int tid = threadIdx.x;
    const int l = tid & 63, wv = tid >> 6;
    const int m = l & 15, q = l >> 4;
    const size_t R0 = (size_t)blockIdx.x * 64 + wv * 16;
    const size_t rowA = (R0 + m) * 512;
    f32x4 acc0 = {0.f,0.f,0.f,0.f}, acc1 = {0.f,0.f,0.f,0.f};
    #pragma unroll
    for (int kk = 0; kk < 32; ++kk) {
        int k0 = kk * 32 + q * 8;
        const bf16* asrc = (k0 < 512) ? (hs_f + rowA + k0) : (hs_b + rowA + (k0 - 512));
        bf16x8 a  = *(const bf16x8*)asrc;
        bf16x8 b0 = *(const bf16x8*)(wlin + (size_t)m * 1024 + k0);
        bf16x8 b1 = *(const bf16x8*)(wlin + (size_t)(16 + m) * 1024 + k0);
        acc0 = __builtin_amdgcn_mfma_f32_16x16x32_bf16(a, b0, acc0, 0, 0, 0);
        acc1 = __builtin_amdgcn_mfma_f32_16x16x32_bf16(a, b1, acc1, 0, 0, 0);
    }
    float lb0 = lin_b[m], lb1 = lin_b[16 + m];
    #pragma unroll
    for (int reg = 0; reg < 4; ++reg) {
        size_t row = R0 + q * 4 + reg;
        logits[row * 32 + m]      = acc0[reg] + lb0;
        logits[row * 32 + 16 + m] = acc1[reg] + lb1;
    }
}

// ---------------- K4: CRF NLL (one wave per batch) ----------------
__global__ void crf_kernel(const float* __restrict__ logits,
                           const int* __restrict__ tags, const int* __restrict__ lengths,
                           const float* __restrict__ startt, const float* __restrict__ endt,
                           const float* __restrict__ trans, float* __restrict__ out)
{
    const int b = blockIdx.x;
    const int l = threadIdx.x;        // 64
    const int j = l & 31, hh = l >> 5;
    const int len = lengths[b];
    const int* tg = tags + b * 512;

    // numerator (parallel over t)
    float s = 0.0f;
    for (int t = 1 + l; t < len; t += 64) {
        int pt = tg[t - 1], ct = tg[t];
        s += trans[pt * 32 + ct] + logits[((size_t)t * 128 + b) * 32 + ct];
    }
    #pragma unroll
    for (int off = 32; off > 0; off >>= 1) s += __shfl_xor(s, off, 64);
    float num = s + startt[tg[0]] + logits[(size_t)b * 32 + tg[0]];

    // denominator (forward algorithm)
    float Tc[16];
    #pragma unroll
    for (int ii = 0; ii < 16; ++ii) Tc[ii] = trans[(hh * 16 + ii) * 32 + j];
    float alpha = startt[j] + logits[(size_t)b * 32 + j];
    for (int t = 1; t < len; ++t) {
        float e = logits[((size_t)t * 128 + b) * 32 + j];
        float v[16];
        #pragma unroll
        for (int ii = 0; ii < 16; ++ii) v[ii] = __shfl(alpha, hh * 16 + ii, 64) + Tc[ii];
        float mx = v[0];
        #pragma unroll
        for (int ii = 1; ii < 16; ++ii) mx = fmaxf(mx, v[ii]);
        mx = fmaxf(mx, __shfl_xor(mx, 32, 64));
        float sm = 0.0f;
        #pragma unroll
        for (int ii = 0; ii < 16; ++ii) sm += __expf(v[ii] - mx);
        sm += __shfl_xor(sm, 32, 64);
        alpha = e + mx + __logf(sm);
    }
    float fvv = alpha + endt[j];
    float mx = fvv;
    #pragma unroll
    for (int off = 16; off > 0; off >>= 1) mx = fmaxf(mx, __shfl_xor(mx, off, 64));
    float sm = __expf(fvv - mx);
    #pragma unroll
    for (int off = 16; off > 0; off >>= 1) sm += __shfl_xor(sm, off, 64);
    float den = mx + __logf(sm);
    if (l == 0) atomicAdd(out, den - num);
}

extern "C" void kernel_launch(void* const* d_in, const int* in_sizes, int n_in,
                              void* d_out, int out_size, void* d_ws, size_t ws_size,
                              hipStream_t stream) {
    const int*   sents   = (const int*)d_in[0];
    const int*   lengths = (const int*)d_in[1];
    const int*   tags    = (const int*)d_in[2];
    // d_in[3] = mask: recomputed from lengths, unused
    const float* table   = (const float*)d_in[4];
    const float* w_ih_f  = (const float*)d_in[5];
    const float* w_hh_f  = (const float*)d_in[6];
    const float* b_ih_f  = (const float*)d_in[7];
    const float* b_hh_f  = (const float*)d_in[8];
    const float* w_ih_b  = (const float*)d_in[9];
    const float* w_hh_b  = (const float*)d_in[10];
    const float* b_ih_b  = (const float*)d_in[11];
    const float* b_hh_b  = (const float*)d_in[12];
    const float* lin_w   = (const float*)d_in[13];
    const float* lin_b   = (const float*)d_in[14];
    const float* startt  = (const float*)d_in[15];
    const float* endt    = (const float*)d_in[16];
    const float* trans   = (const float*)d_in[17];

    char* wsb = (char*)d_ws;
    bf16*  emb    = (bf16*)(wsb + EMB_OFF);
    bf16*  hs_f   = (bf16*)(wsb + HSF_OFF);
    bf16*  hs_b   = (bf16*)(wsb + HSB_OFF);
    float* logits = (float*)(wsb + LOG_OFF);
    bf16*  hping  = (bf16*)(wsb + HPING_OFF);
    bf16*  wlin   = (bf16*)(wsb + WLIN_OFF);
    int*   bar    = (int*)(wsb + BAR_OFF);

    hipMemsetAsync(d_out, 0, sizeof(float), stream);
    hipMemsetAsync(bar, 0, BAR_SZ, stream);

    embed_gather<<<8192, 256, 0, stream>>>(sents, table, emb);
    conv_linw<<<128, 256, 0, stream>>>(lin_w, wlin);

    void* args[] = { &emb, &hping, &hs_f, &hs_b,
                     &w_ih_f, &w_hh_f, &b_ih_f, &b_hh_f,
                     &w_ih_b, &w_hh_b, &b_ih_b, &b_hh_b,
                     &lengths, &bar };
    hipError_t e = hipLaunchCooperativeKernel((const void*)lstm_persistent,
                                              dim3(256), dim3(256), args, 0, stream);
    if (e != hipSuccess) {
        // fallback: 256 blocks of this config are de-facto co-resident (1 block/CU)
        lstm_persistent<<<256, 256, 0, stream>>>(emb, hping, hs_f, hs_b,
            w_ih_f, w_hh_f, b_ih_f, b_hh_f, w_ih_b, w_hh_b, b_ih_b, b_hh_b,
            lengths, bar);
    }

    logits_kernel<<<1024, 256, 0, stream>>>(hs_f, hs_b, wlin, lin_b, logits);
    crf_kernel<<<128, 64, 0, stream>>>(logits, tags, lengths, startt, endt, trans,
                                       (float*)d_out);
}

// Round 2
// 2823.119 us; speedup vs baseline: 4.9857x; 4.9857x over previous
//
#include <hip/hip_runtime.h>
#include <hip/hip_bf16.h>
#include <cstdint>
#include <cstddef>

typedef __bf16 bf16;
typedef __bf16 bf16x8 __attribute__((ext_vector_type(8)));
typedef float f32x4 __attribute__((ext_vector_type(4)));

#define B_ 128
#define S_ 512
#define E_ 256
#define H_ 512

// ---- workspace layout (bytes) ----
#define EMB_OFF   0UL
#define EMB_SZ    (128UL*512*256*2)        // 33,554,432  bf16 (B,S,E)
#define HSF_OFF   (EMB_OFF + EMB_SZ)
#define HS_SZ     (512UL*128*512*2)        // 67,108,864  bf16 (S,B,H)
#define HSB_OFF   (HSF_OFF + HS_SZ)
#define LOG_OFF   (HSB_OFF + HS_SZ)
#define LOG_SZ    (512UL*128*32*4)         // 8,388,608   f32 (S,B,T)
#define HPING_OFF (LOG_OFF + LOG_SZ)
#define HPING_SZ  (16UL*2*16*512*2)        // 524,288     bf16 [group][2][16][512]
#define WLIN_OFF  (HPING_OFF + HPING_SZ)
#define WLIN_SZ   (32UL*1024*2)            // 65,536      bf16
#define BAR_OFF   ((WLIN_OFF + WLIN_SZ + 255UL) & ~255UL)
#define BAR_SZ    (16UL*16*32*4)           // 16 groups * 16 slots * 128B

#define LD_AG(p)    __hip_atomic_load((p),  __ATOMIC_RELAXED, __HIP_MEMORY_SCOPE_AGENT)
#define ST_AG(p,v)  __hip_atomic_store((p), (v), __ATOMIC_RELAXED, __HIP_MEMORY_SCOPE_AGENT)

__device__ __forceinline__ float fsig(float x)  { return 1.0f / (1.0f + __expf(-x)); }
__device__ __forceinline__ float ftanhf(float x){ return 1.0f - 2.0f / (__expf(2.0f * x) + 1.0f); }

// ---------------- K1: embedding gather fp32 -> bf16 ----------------
__global__ void embed_gather(const int* __restrict__ sents,
                             const float* __restrict__ table,
                             bf16* __restrict__ emb) {
    int t = threadIdx.x;
    int row = blockIdx.x * 8 + (t >> 5);       // flat (b,s), 65536 rows
    int e0 = (t & 31) * 8;
    int idx = sents[row];
    const float4* src = (const float4*)(table + (size_t)idx * 256 + e0);
    float4 f0 = src[0], f1 = src[1];
    bf16x8 v;
    v[0]=(bf16)f0.x; v[1]=(bf16)f0.y; v[2]=(bf16)f0.z; v[3]=(bf16)f0.w;
    v[4]=(bf16)f1.x; v[5]=(bf16)f1.y; v[6]=(bf16)f1.z; v[7]=(bf16)f1.w;
    *(bf16x8*)(emb + (size_t)row * 256 + e0) = v;
}

// ---------------- K1b: lin_w fp32 -> bf16 ----------------
__global__ void conv_linw(const float* __restrict__ w, bf16* __restrict__ o) {
    int i = blockIdx.x * 256 + threadIdx.x;    // 32768
    o[i] = (bf16)w[i];
}

// ---------------- K2: persistent bidirectional LSTM ----------------
// grid 256 x 256. 16 groups = (dir, batch-tile of 16); 16 WGs/group (32 hidden units each).
// Per wave: M=16 (batch), N=32 (2 MFMA n-tiles; cols = gate(i,f | g,o) x 8 units), K=768.
// Weights resident in VGPRs. A staged in LDS in fragment order.
// Cross-WG h exchange via relaxed agent-scope (sc1) atomics — NO fences in the loop.
__global__ __launch_bounds__(256, 1) void lstm_persistent(
    const bf16* __restrict__ emb, bf16* __restrict__ hping,
    bf16* __restrict__ hs_f, bf16* __restrict__ hs_b,
    const float* __restrict__ w_ih_f, const float* __restrict__ w_hh_f,
    const float* __restrict__ b_ih_f, const float* __restrict__ b_hh_f,
    const float* __restrict__ w_ih_b, const float* __restrict__ w_hh_b,
    const float* __restrict__ b_ih_b, const float* __restrict__ b_hh_b,
    const int* __restrict__ lengths, int* __restrict__ bar)
{
    const int tid = threadIdx.x;
    const int l   = tid & 63;
    const int wv  = tid >> 6;
    const int bid = blockIdx.x;
    const int slot = bid >> 3;
    const int g  = (bid & 7) + ((slot >> 4) << 3);   // 0..15
    const int k  = slot & 15;                        // hidden group 0..15
    const int d  = g >> 3;                           // 0 fwd, 1 bwd
    const int bg = g & 7;                            // batch tile
    const int U0 = k * 32;

    const float* Wih = d ? w_ih_b : w_ih_f;
    const float* Whh = d ? w_hh_b : w_hh_f;
    const float* Bih = d ? b_ih_b : b_ih_f;
    const float* Bhh = d ? b_hh_b : b_hh_f;

    __shared__ uint4 smemA[1536];          // 24 KB: A fragments (24 K-chunks x 64 slots)
    __shared__ float gatesS[16 * 132];     // raw gate pre-activations
    __shared__ float c_sh[512];
    __shared__ float h_sh[512];
    __shared__ int   sh_tmax;

    // ---- weight fragments into VGPRs (once) ----
    bf16x8 wf[24][2];
    {
        const int lane15 = l & 15, q = l >> 4;
        #pragma unroll
        for (int kk = 0; kk < 24; ++kk) {
            #pragma unroll
            for (int T = 0; T < 2; ++T) {
                int c   = T * 16 + lane15;                       // within-wave col 0..31
                int row = (c >> 3) * 512 + U0 + 8 * wv + (c & 7); // W row (gate*512+unit)
                int k0  = kk * 32 + q * 8;
                const float* src = (k0 < 256) ? (Wih + (size_t)row * 256 + k0)
                                              : (Whh + (size_t)row * 512 + (k0 - 256));
                float4 f0 = *(const float4*)src;
                float4 f1 = *(const float4*)(src + 4);
                bf16x8 v;
                v[0]=(bf16)f0.x; v[1]=(bf16)f0.y; v[2]=(bf16)f0.z; v[3]=(bf16)f0.w;
                v[4]=(bf16)f1.x; v[5]=(bf16)f1.y; v[6]=(bf16)f1.z; v[7]=(bf16)f1.w;
                wf[kk][T] = v;
            }
        }
    }

    // ---- per-thread updater setup ----
    const int uu = tid & 31;        // unit within WG (0..31)
    const int ub = tid >> 5;        // 0..7
    float bI, bF, bG, bO;
    {
        int r0 = U0 + uu;
        bI = Bih[r0]        + Bhh[r0];
        bF = Bih[512 + r0]  + Bhh[512 + r0];
        bG = Bih[1024 + r0] + Bhh[1024 + r0];
        bO = Bih[1536 + r0] + Bhh[1536 + r0];
    }
    int lenU0 = lengths[bg * 16 + ub * 2];
    int lenU1 = lengths[bg * 16 + ub * 2 + 1];

    // ---- staging thread setup ----
    const int sr  = tid & 15;       // batch row 0..15
    const int sc0 = tid >> 4;       // chunk col 0..15
    const int lenR = lengths[bg * 16 + sr];
    const bf16* embB = emb + ((size_t)(bg * 16 + sr)) * 512 * 256;

    // ---- zero state ----
    for (int i = tid; i < 512; i += 256) { c_sh[i] = 0.0f; h_sh[i] = 0.0f; }
    bf16* hp = hping + (size_t)g * (2 * 16 * 512);
    {
        int r = tid >> 4, cc = tid & 15;
        unsigned int* p = (unsigned int*)(hp + r * 512 + U0 + cc * 2);
        ST_AG(p, 0u);
    }
    if (tid == 0) {
        int mx = 0;
        for (int b2 = 0; b2 < 16; ++b2) mx = max(mx, lengths[bg * 16 + b2]);
        sh_tmax = mx;
    }
    __builtin_amdgcn_s_waitcnt(0x0f70);    // vmcnt(0): our sc1 zero-stores at LLC
    __syncthreads();
    const int tmax = sh_tmax;

    int* slots  = bar + g * 16 * 32;       // 16 epoch slots, 128B apart
    int* myslot = slots + k * 32;
    int* pollp  = slots + (tid & 15) * 32;
    if (tid == 0) ST_AG(myslot, 1);        // epoch 1: h buffer 0 ready

    const int sig = 4 * (l & 15) + (l >> 4);

    for (int t = 0; t < tmax; ++t) {
        bf16* hcur = hp + (t & 1) * (16 * 512);
        bf16* hnxt = hp + ((t + 1) & 1) * (16 * 512);

        // ---- stage emb part of A (h-independent: overlaps barrier wait) ----
        int pos = (d == 0) ? t : ((t < lenR) ? (lenR - 1 - t) : t);
        const bf16* xsrc = embB + (size_t)pos * 256;
        #pragma unroll
        for (int i = 0; i < 2; ++i) {
            int c = sc0 + 16 * i;
            uint4 v = *(const uint4*)(xsrc + c * 8);
            smemA[((c >> 2) << 6) + 4 * sr + (c & 3)] = v;
        }

        // ---- wait: all 16 WGs of group published epoch >= t+1 ----
        if (tid < 16) {
            while (LD_AG(pollp) < t + 1) {}
        }
        __syncthreads();

        // ---- stage h part of A (sc1 loads straight from LLC) ----
        #pragma unroll
        for (int i = 2; i < 6; ++i) {
            int c = sc0 + 16 * i;
            unsigned int* src = (unsigned int*)(hcur + sr * 512 + (c - 32) * 8);
            uint4 v;
            v.x = LD_AG(src + 0);
            v.y = LD_AG(src + 1);
            v.z = LD_AG(src + 2);
            v.w = LD_AG(src + 3);
            smemA[((c >> 2) << 6) + 4 * sr + (c & 3)] = v;
        }
        __syncthreads();

        // ---- MFMA: gates = A * W^T ----
        f32x4 acc0 = {0.f, 0.f, 0.f, 0.f}, acc1 = {0.f, 0.f, 0.f, 0.f};
        #pragma unroll
        for (int kk = 0; kk < 24; ++kk) {
            bf16x8 a = *(const bf16x8*)&smemA[(kk << 6) + sig];
            acc0 = __builtin_amdgcn_mfma_f32_16x16x32_bf16(a, wf[kk][0], acc0, 0, 0, 0);
            acc1 = __builtin_amdgcn_mfma_f32_16x16x32_bf16(a, wf[kk][1], acc1, 0, 0, 0);
        }
        // ---- write gates to LDS, permuted so (i,f,g,o) of a unit are contiguous ----
        {
            int c0l = l & 15;
            int colA = (wv << 5) + ((c0l & 7) << 2) + (c0l >> 3);       // gates 0/1
            int colB = colA + 2;                                        // gates 2/3
            int rbase = (l >> 4) * 4;
            #pragma unroll
            for (int reg = 0; reg < 4; ++reg) {
                gatesS[(rbase + reg) * 132 + colA] = acc0[reg];
                gatesS[(rbase + reg) * 132 + colB] = acc1[reg];
            }
        }
        __syncthreads();

        // ---- cell update (2 (b,u) pairs per thread) ----
        #pragma unroll
        for (int bi = 0; bi < 2; ++bi) {
            int b   = ub * 2 + bi;
            int len = bi ? lenU1 : lenU0;
            float4 gv = *(const float4*)&gatesS[b * 132 + ((uu >> 3) << 5) + ((uu & 7) << 2)];
            float iv = fsig(gv.x + bI);
            float fv = fsig(gv.y + bF);
            float gg = ftanhf(gv.z + bG);
            float ov = fsig(gv.w + bO);
            int si = b * 32 + uu;
            float co = c_sh[si], ho = h_sh[si];
            float cn = fv * co + iv * gg;
            float hn = ov * ftanhf(cn);
            bool m = (t < len);
            float cw = m ? cn : co;
            float hw = m ? hn : ho;
            c_sh[si] = cw; h_sh[si] = hw;
            bf16 hb = (bf16)hw;
            ST_AG((unsigned short*)(hnxt + b * 512 + U0 + uu),
                  __builtin_bit_cast(unsigned short, hb));
            if (d == 0) {
                hs_f[((size_t)t * 128 + bg * 16 + b) * 512 + U0 + uu] = hb;
            } else if (m) {
                hs_b[((size_t)(len - 1 - t) * 128 + bg * 16 + b) * 512 + U0 + uu] = hb;
            }
        }

        // ---- publish epoch t+2 (h[t+1] ready) ----
        __builtin_amdgcn_s_waitcnt(0x0f70);    // each wave: its sc1 h-stores at LLC
        __syncthreads();
        if (tid == 0) ST_AG(myslot, t + 2);
    }
}

// ---------------- K3: logits = [hs_f|hs_b] @ lin_w^T + lin_b ----------------
__global__ __launch_bounds__(256) void logits_kernel(
    const bf16* __restrict__ hs_f, const bf16* __restrict__ hs_b,
    const bf16* __restrict__ wlin, const float* __restrict__ lin_b,
    float* __restrict__ logits)
{
    const int tid = threadIdx.x;
    const int l = tid & 63, wv = tid >> 6;
    const int m = l & 15, q = l >> 4;
    const size_t R0 = (size_t)blockIdx.x * 64 + wv * 16;
    const size_t rowA = (R0 + m) * 512;
    f32x4 acc0 = {0.f,0.f,0.f,0.f}, acc1 = {0.f,0.f,0.f,0.f};
    #pragma unroll
    for (int kk = 0; kk < 32; ++kk) {
        int k0 = kk * 32 + q * 8;
        const bf16* asrc = (k0 < 512) ? (hs_f + rowA + k0) : (hs_b + rowA + (k0 - 512));
        bf16x8 a  = *(const bf16x8*)asrc;
        bf16x8 b0 = *(const bf16x8*)(wlin + (size_t)m * 1024 + k0);
        bf16x8 b1 = *(const bf16x8*)(wlin + (size_t)(16 + m) * 1024 + k0);
        acc0 = __builtin_amdgcn_mfma_f32_16x16x32_bf16(a, b0, acc0, 0, 0, 0);
        acc1 = __builtin_amdgcn_mfma_f32_16x16x32_bf16(a, b1, acc1, 0, 0, 0);
    }
    float lb0 = lin_b[m], lb1 = lin_b[16 + m];
    #pragma unroll
    for (int reg = 0; reg < 4; ++reg) {
        size_t row = R0 + q * 4 + reg;
        logits[row * 32 + m]      = acc0[reg] + lb0;
        logits[row * 32 + 16 + m] = acc1[reg] + lb1;
    }
}

// ---------------- K4: CRF NLL (one wave per batch) ----------------
__global__ void crf_kernel(const float* __restrict__ logits,
                           const int* __restrict__ tags, const int* __restrict__ lengths,
                           const float* __restrict__ startt, const float* __restrict__ endt,
                           const float* __restrict__ trans, float* __restrict__ out)
{
    const int b = blockIdx.x;
    const int l = threadIdx.x;        // 64
    const int j = l & 31, hh = l >> 5;
    const int len = lengths[b];
    const int* tg = tags + b * 512;

    // numerator (parallel over t)
    float s = 0.0f;
    for (int t = 1 + l; t < len; t += 64) {
        int pt = tg[t - 1], ct = tg[t];
        s += trans[pt * 32 + ct] + logits[((size_t)t * 128 + b) * 32 + ct];
    }
    #pragma unroll
    for (int off = 32; off > 0; off >>= 1) s += __shfl_xor(s, off, 64);
    float num = s + startt[tg[0]] + logits[(size_t)b * 32 + tg[0]];

    // denominator (forward algorithm)
    float Tc[16];
    #pragma unroll
    for (int ii = 0; ii < 16; ++ii) Tc[ii] = trans[(hh * 16 + ii) * 32 + j];
    float alpha = startt[j] + logits[(size_t)b * 32 + j];
    for (int t = 1; t < len; ++t) {
        float e = logits[((size_t)t * 128 + b) * 32 + j];
        float v[16];
        #pragma unroll
        for (int ii = 0; ii < 16; ++ii) v[ii] = __shfl(alpha, hh * 16 + ii, 64) + Tc[ii];
        float mx = v[0];
        #pragma unroll
        for (int ii = 1; ii < 16; ++ii) mx = fmaxf(mx, v[ii]);
        mx = fmaxf(mx, __shfl_xor(mx, 32, 64));
        float sm = 0.0f;
        #pragma unroll
        for (int ii = 0; ii < 16; ++ii) sm += __expf(v[ii] - mx);
        sm += __shfl_xor(sm, 32, 64);
        alpha = e + mx + __logf(sm);
    }
    float fvv = alpha + endt[j];
    float mx = fvv;
    #pragma unroll
    for (int off = 16; off > 0; off >>= 1) mx = fmaxf(mx, __shfl_xor(mx, off, 64));
    float sm = __expf(fvv - mx);
    #pragma unroll
    for (int off = 16; off > 0; off >>= 1) sm += __shfl_xor(sm, off, 64);
    float den = mx + __logf(sm);
    if (l == 0) atomicAdd(out, den - num);
}

extern "C" void kernel_launch(void* const* d_in, const int* in_sizes, int n_in,
                              void* d_out, int out_size, void* d_ws, size_t ws_size,
                              hipStream_t stream) {
    const int*   sents   = (const int*)d_in[0];
    const int*   lengths = (const int*)d_in[1];
    const int*   tags    = (const int*)d_in[2];
    // d_in[3] = mask: recomputed from lengths, unused
    const float* table   = (const float*)d_in[4];
    const float* w_ih_f  = (const float*)d_in[5];
    const float* w_hh_f  = (const float*)d_in[6];
    const float* b_ih_f  = (const float*)d_in[7];
    const float* b_hh_f  = (const float*)d_in[8];
    const float* w_ih_b  = (const float*)d_in[9];
    const float* w_hh_b  = (const float*)d_in[10];
    const float* b_ih_b  = (const float*)d_in[11];
    const float* b_hh_b  = (const float*)d_in[12];
    const float* lin_w   = (const float*)d_in[13];
    const float* lin_b   = (const float*)d_in[14];
    const float* startt  = (const float*)d_in[15];
    const float* endt    = (const float*)d_in[16];
    const float* trans   = (const float*)d_in[17];

    char* wsb = (char*)d_ws;
    bf16*  emb    = (bf16*)(wsb + EMB_OFF);
    bf16*  hs_f   = (bf16*)(wsb + HSF_OFF);
    bf16*  hs_b   = (bf16*)(wsb + HSB_OFF);
    float* logits = (float*)(wsb + LOG_OFF);
    bf16*  hping  = (bf16*)(wsb + HPING_OFF);
    bf16*  wlin   = (bf16*)(wsb + WLIN_OFF);
    int*   bar    = (int*)(wsb + BAR_OFF);

    hipMemsetAsync(d_out, 0, sizeof(float), stream);
    hipMemsetAsync(bar, 0, BAR_SZ, stream);

    embed_gather<<<8192, 256, 0, stream>>>(sents, table, emb);
    conv_linw<<<128, 256, 0, stream>>>(lin_w, wlin);

    void* args[] = { &emb, &hping, &hs_f, &hs_b,
                     &w_ih_f, &w_hh_f, &b_ih_f, &b_hh_f,
                     &w_ih_b, &w_hh_b, &b_ih_b, &b_hh_b,
                     &lengths, &bar };
    hipError_t e = hipLaunchCooperativeKernel((const void*)lstm_persistent,
                                              dim3(256), dim3(256), args, 0, stream);
    if (e != hipSuccess) {
        lstm_persistent<<<256, 256, 0, stream>>>(emb, hping, hs_f, hs_b,
            w_ih_f, w_hh_f, b_ih_f, b_hh_f, w_ih_b, w_hh_b, b_ih_b, b_hh_b,
            lengths, bar);
    }

    logits_kernel<<<1024, 256, 0, stream>>>(hs_f, hs_b, wlin, lin_b, logits);
    crf_kernel<<<128, 64, 0, stream>>>(logits, tags, lengths, startt, endt, trans,
                                       (float*)d_out);
}